// Round 4
// baseline (27.645 us; speedup 1.0000x reference)
//
#include <hip/hip_runtime.h>

// ESN scan: out[b,c,t,r] = s_t, s_t = tanh(x[b,c,t]*w[r] + s_{t-1}*d[r]).
// B=32 C=8 T=512 R=256. One block (256 thr) per (b,c), one thread per r-chain.
//
// R1: x staged in LDS -> no global loads in the loop (stores never vmcnt-waited).
// R2: carried chain = {exp2, add, rcp, fma}; stored value off-chain.  [neutral]
// R3: stores widened dword -> dwordx4 via LDS transpose. Rationale: store
//     in-flight bytes are capped by expcnt (3-bit, <=7 outstanding per wave)
//     -> 4 waves x 7 x 256B = 7KB/CU = ~5 TB/s observed. 1KB wave-stores give
//     28KB/CU in flight -> HBM write ceiling. One barrier per 16-step group,
//     double-buffered transpose LDS.

constexpr int Bdim = 32;
constexpr int Cdim = 8;
constexpr int Tdim = 512;
constexpr int Rdim = 256;
constexpr int T4   = Tdim / 4;   // 128 float4 of x per row
constexpr int GS   = 16;         // time steps per group
constexpr int NG   = Tdim / GS;  // 32 groups

__device__ __forceinline__ float fast_exp2(float v) {
#if defined(__has_builtin)
#if __has_builtin(__builtin_amdgcn_exp2f)
    return __builtin_amdgcn_exp2f(v);
#else
    return exp2f(v);
#endif
#else
    return exp2f(v);
#endif
}

__global__ __launch_bounds__(256, 1) void esn_scan_kernel(
    const float* __restrict__ x,     // [B*C, T]
    const float* __restrict__ W_in,  // [R] (R,1 flattened)
    const float* __restrict__ d,     // [R]
    float* __restrict__ out)         // [B*C, T, R]
{
    const int bc = blockIdx.x;
    const int r  = threadIdx.x;
    const int w  = r >> 6;    // wave id 0..3
    const int l  = r & 63;    // lane id

    // tanh(a) = 1 - 2/(exp2(K*a)+1), K = 2*log2(e); fold K into w,d.
    const float K    = 2.0f * 1.4426950408889634f;
    const float wk   = W_in[r] * K;
    const float dk   = d[r] * K;
    const float m2dk = -2.0f * dk;

    __shared__ float4 xs4[T4];            // 2 KiB: this row's x
    __shared__ float4 ssb[2][GS][64];     // 2 x 16 KiB transpose buffers

    {
        const float4* __restrict__ x4 = reinterpret_cast<const float4*>(x + bc * Tdim);
        if (r < T4) xs4[r] = x4[r];
    }
    __syncthreads();

    float4* __restrict__ orow =
        reinterpret_cast<float4*>(out + (size_t)bc * Tdim * Rdim);

    // Group g consumes xs4[4g .. 4g+3]; keep current group in regs, prefetch next.
    float4 a0 = xs4[0], a1 = xs4[1], a2 = xs4[2], a3 = xs4[3];
    float earg = a0.x * wk;   // t=0 argument (s_init = 0)

    #pragma unroll 1
    for (int g = 0; g < NG; ++g) {
        int pf = 4 * g + 4; if (pf > T4 - 4) pf = T4 - 4;   // clamped (tail dead)
        float4 n0 = xs4[pf], n1 = xs4[pf + 1], n2 = xs4[pf + 2], n3 = xs4[pf + 3];

        // Off-chain successor-arg pre-adds: pre_j = x_{t+1}*wk + dk.
        float pre[GS];
        pre[0]  = fmaf(a0.y, wk, dk);
        pre[1]  = fmaf(a0.z, wk, dk);
        pre[2]  = fmaf(a0.w, wk, dk);
        pre[3]  = fmaf(a1.x, wk, dk);
        pre[4]  = fmaf(a1.y, wk, dk);
        pre[5]  = fmaf(a1.z, wk, dk);
        pre[6]  = fmaf(a1.w, wk, dk);
        pre[7]  = fmaf(a2.x, wk, dk);
        pre[8]  = fmaf(a2.y, wk, dk);
        pre[9]  = fmaf(a2.z, wk, dk);
        pre[10] = fmaf(a2.w, wk, dk);
        pre[11] = fmaf(a3.x, wk, dk);
        pre[12] = fmaf(a3.y, wk, dk);
        pre[13] = fmaf(a3.z, wk, dk);
        pre[14] = fmaf(a3.w, wk, dk);
        pre[15] = fmaf(n0.x, wk, dk);   // next group's t0 (dead on last group)

        // 16 recurrence steps; s written to LDS (stride-1 across lanes).
        float* sb = reinterpret_cast<float*>(&ssb[g & 1][0][0]);
        #pragma unroll
        for (int j = 0; j < GS; ++j) {
            float e  = fast_exp2(earg);
            float rc = __builtin_amdgcn_rcpf(e + 1.0f);
            sb[j * Rdim + r] = fmaf(-2.0f, rc, 1.0f);
            earg = fmaf(m2dk, rc, pre[j]);
        }
        __syncthreads();

        // Transposed read-back: thread (w,l) takes t-sub = w+4k, r = 4l..4l+3,
        // i.e. wave-contiguous 1KB, then 4x global_store_dwordx4.
        const float4* __restrict__ sr = &ssb[g & 1][0][0];
        float4 v0 = sr[(w     ) * 64 + l];
        float4 v1 = sr[(w +  4) * 64 + l];
        float4 v2 = sr[(w +  8) * 64 + l];
        float4 v3 = sr[(w + 12) * 64 + l];

        const size_t tb = (size_t)(g * GS) * 64;   // float4-index of group base
        orow[tb + (size_t)(w     ) * 64 + l] = v0;
        orow[tb + (size_t)(w +  4) * 64 + l] = v1;
        orow[tb + (size_t)(w +  8) * 64 + l] = v2;
        orow[tb + (size_t)(w + 12) * 64 + l] = v3;

        a0 = n0; a1 = n1; a2 = n2; a3 = n3;
    }
}

extern "C" void kernel_launch(void* const* d_in, const int* in_sizes, int n_in,
                              void* d_out, int out_size, void* d_ws, size_t ws_size,
                              hipStream_t stream) {
    const float* x    = (const float*)d_in[0];  // [B,C,T]
    const float* W_in = (const float*)d_in[1];  // [R,1]
    const float* d    = (const float*)d_in[2];  // [R]
    float* out        = (float*)d_out;          // [B,C,T,R]

    dim3 grid(Bdim * Cdim);
    dim3 block(Rdim);
    esn_scan_kernel<<<grid, block, 0, stream>>>(x, W_in, d, out);
}